// Round 3
// baseline (1385.805 us; speedup 1.0000x reference)
//
#include <hip/hip_runtime.h>
#include <math.h>

#define N_NODES   50000
#define N_EDGES   800000
#define IN_FEAT   64
#define HIDDEN    32
#define GRID_SZ   4
#define N_GRAPHS  128
#define NEG_SLOPE 0.01f

// ---------------------------------------------------------------------------
__global__ __launch_bounds__(256) void zero_kernel(float* __restrict__ p, int n) {
  const int i = blockIdx.x * 256 + threadIdx.x;
  if (i < n) p[i] = 0.f;
}

// ---------------------------------------------------------------------------
// One thread per node. Weights (2,32,64,4)=64KB staged in LDS, read via
// wave-uniform broadcast (conflict-free). Features + 32 accumulators in regs.
// ---------------------------------------------------------------------------
__global__ __launch_bounds__(256) void kan_input_v2(
    const float* __restrict__ X, const float* __restrict__ W,
    float* __restrict__ H) {
  __shared__ float w[2 * HIDDEN * IN_FEAT * GRID_SZ];  // 16384 floats
  const int tid = threadIdx.x;
  for (int idx = tid; idx < 4096; idx += 256)
    reinterpret_cast<float4*>(w)[idx] = reinterpret_cast<const float4*>(W)[idx];
  __syncthreads();

  const int node = blockIdx.x * 256 + tid;
  if (node >= N_NODES) return;
  const float* __restrict__ xr = X + node * IN_FEAT;

  float acc[HIDDEN];
#pragma unroll
  for (int o = 0; o < HIDDEN; ++o) acc[o] = 0.f;

  for (int i4 = 0; i4 < IN_FEAT / 4; ++i4) {
    const float4 xv = reinterpret_cast<const float4*>(xr)[i4];
#pragma unroll
    for (int j = 0; j < 4; ++j) {
      const int i = i4 * 4 + j;
      const float v = (j == 0) ? xv.x : (j == 1) ? xv.y : (j == 2) ? xv.z : xv.w;
      float s1, c1;
      sincosf(v, &s1, &c1);
      const float cs0 = c1,               sn0 = s1;
      const float cs1 = cs0*c1 - sn0*s1,  sn1 = sn0*c1 + cs0*s1;
      const float cs2 = cs1*c1 - sn1*s1,  sn2 = sn1*c1 + cs1*s1;
      const float cs3 = cs2*c1 - sn2*s1,  sn3 = sn2*c1 + cs2*s1;
      const float* __restrict__ w0 = w + i * GRID_SZ;           // + o*256
      const float* __restrict__ w1 = w + 8192 + i * GRID_SZ;
#pragma unroll
      for (int o = 0; o < HIDDEN; ++o) {
        const float4 a = *reinterpret_cast<const float4*>(w0 + o * (IN_FEAT * GRID_SZ));
        const float4 b = *reinterpret_cast<const float4*>(w1 + o * (IN_FEAT * GRID_SZ));
        acc[o] += cs0*a.x + cs1*a.y + cs2*a.z + cs3*a.w
                + sn0*b.x + sn1*b.y + sn2*b.z + sn3*b.w;
      }
    }
  }
  float* __restrict__ hr = H + node * HIDDEN;
#pragma unroll
  for (int o4 = 0; o4 < HIDDEN / 4; ++o4)
    reinterpret_cast<float4*>(hr)[o4] =
        make_float4(acc[o4*4], acc[o4*4+1], acc[o4*4+2], acc[o4*4+3]);
}

// ---------------------------------------------------------------------------
// Conv-layer KAN, one thread per node. W layer (2,32,32,4)=32KB in LDS.
// Optionally fuses the previous layer's update: hv = leaky_relu(M+H), H=hv.
// ---------------------------------------------------------------------------
__global__ __launch_bounds__(256) void kan_node_v2(
    const float* __restrict__ Hin, const float* __restrict__ Min,
    const float* __restrict__ W, float* __restrict__ T,
    float* __restrict__ Hout) {
  __shared__ float w[2 * HIDDEN * HIDDEN * GRID_SZ];  // 8192 floats
  const int tid = threadIdx.x;
  for (int idx = tid; idx < 2048; idx += 256)
    reinterpret_cast<float4*>(w)[idx] = reinterpret_cast<const float4*>(W)[idx];
  __syncthreads();

  const int node = blockIdx.x * 256 + tid;
  if (node >= N_NODES) return;

  float hv[HIDDEN];
  const float* __restrict__ hr = Hin + node * HIDDEN;
  if (Min != nullptr) {
    const float* __restrict__ mr = Min + node * HIDDEN;
    float* __restrict__ ho = Hout + node * HIDDEN;
#pragma unroll
    for (int i4 = 0; i4 < HIDDEN / 4; ++i4) {
      const float4 h4 = reinterpret_cast<const float4*>(hr)[i4];
      const float4 m4 = reinterpret_cast<const float4*>(mr)[i4];
      float4 u;
      u.x = h4.x + m4.x; u.x = (u.x >= 0.f) ? u.x : NEG_SLOPE * u.x;
      u.y = h4.y + m4.y; u.y = (u.y >= 0.f) ? u.y : NEG_SLOPE * u.y;
      u.z = h4.z + m4.z; u.z = (u.z >= 0.f) ? u.z : NEG_SLOPE * u.z;
      u.w = h4.w + m4.w; u.w = (u.w >= 0.f) ? u.w : NEG_SLOPE * u.w;
      reinterpret_cast<float4*>(ho)[i4] = u;
      hv[i4*4+0] = u.x; hv[i4*4+1] = u.y; hv[i4*4+2] = u.z; hv[i4*4+3] = u.w;
    }
  } else {
#pragma unroll
    for (int i4 = 0; i4 < HIDDEN / 4; ++i4) {
      const float4 h4 = reinterpret_cast<const float4*>(hr)[i4];
      hv[i4*4+0] = h4.x; hv[i4*4+1] = h4.y; hv[i4*4+2] = h4.z; hv[i4*4+3] = h4.w;
    }
  }

  float acc[HIDDEN];
#pragma unroll
  for (int o = 0; o < HIDDEN; ++o) acc[o] = 0.f;

#pragma unroll 4
  for (int i = 0; i < HIDDEN; ++i) {
    const float v = hv[i];
    float s1, c1;
    sincosf(v, &s1, &c1);
    const float cs0 = c1,               sn0 = s1;
    const float cs1 = cs0*c1 - sn0*s1,  sn1 = sn0*c1 + cs0*s1;
    const float cs2 = cs1*c1 - sn1*s1,  sn2 = sn1*c1 + cs1*s1;
    const float cs3 = cs2*c1 - sn2*s1,  sn3 = sn2*c1 + cs2*s1;
    const float* __restrict__ w0 = w + i * GRID_SZ;             // + o*128
    const float* __restrict__ w1 = w + 4096 + i * GRID_SZ;
#pragma unroll
    for (int o = 0; o < HIDDEN; ++o) {
      const float4 a = *reinterpret_cast<const float4*>(w0 + o * (HIDDEN * GRID_SZ));
      const float4 b = *reinterpret_cast<const float4*>(w1 + o * (HIDDEN * GRID_SZ));
      acc[o] += cs0*a.x + cs1*a.y + cs2*a.z + cs3*a.w
              + sn0*b.x + sn1*b.y + sn2*b.z + sn3*b.w;
    }
  }
  float* __restrict__ tr = T + node * HIDDEN;
#pragma unroll
  for (int o4 = 0; o4 < HIDDEN / 4; ++o4)
    reinterpret_cast<float4*>(tr)[o4] =
        make_float4(acc[o4*4], acc[o4*4+1], acc[o4*4+2], acc[o4*4+3]);
}

// ---------------------------------------------------------------------------
// m[dst[e]][f] += t[src[e]][f]   (32 threads per edge)
// ---------------------------------------------------------------------------
__global__ __launch_bounds__(256) void edge_scatter_kernel(
    const float* __restrict__ T, const int* __restrict__ src,
    const int* __restrict__ dst, float* __restrict__ M) {
  const int gid = blockIdx.x * 256 + threadIdx.x;
  const int e = gid >> 5;
  const int f = gid & 31;
  if (e < N_EDGES) {
    const int s = src[e];
    const int d = dst[e];
    atomicAdd(&M[d * HIDDEN + f], T[s * HIDDEN + f]);
  }
}

// ---------------------------------------------------------------------------
// pool with fused final update: v = leaky_relu(M+H); per-graph sums/counts
// ---------------------------------------------------------------------------
__global__ __launch_bounds__(256) void pool_fused(
    const float* __restrict__ H, const float* __restrict__ M,
    const int* __restrict__ batch, float* __restrict__ sums,
    float* __restrict__ cnt) {
  const int gid = blockIdx.x * 256 + threadIdx.x;
  const int n = gid >> 5;
  const int f = gid & 31;
  if (n < N_NODES) {
    const int g = batch[n];
    float v = H[n * HIDDEN + f] + M[n * HIDDEN + f];
    v = (v >= 0.f) ? v : NEG_SLOPE * v;
    atomicAdd(&sums[g * HIDDEN + f], v);
    if (f == 0) atomicAdd(&cnt[g], 1.0f);
  }
}

// ---------------------------------------------------------------------------
__global__ __launch_bounds__(128) void readout_kernel(
    const float* __restrict__ sums, const float* __restrict__ cnt,
    const float* __restrict__ Wout, const float* __restrict__ bout,
    float* __restrict__ out) {
  const int g = threadIdx.x;
  if (g < N_GRAPHS) {
    const float c = fmaxf(cnt[g], 1.0f);
    float z = 0.f;
#pragma unroll
    for (int i = 0; i < HIDDEN; ++i) {
      const float y = sums[g * HIDDEN + i] / c;
      z += cosf(y) * Wout[i] + sinf(y) * Wout[HIDDEN + i];
    }
    z += bout[0];
    out[g] = 1.0f / (1.0f + expf(-z));
  }
}

// ---------------------------------------------------------------------------
extern "C" void kernel_launch(void* const* d_in, const int* in_sizes, int n_in,
                              void* d_out, int out_size, void* d_ws, size_t ws_size,
                              hipStream_t stream) {
  const float* x        = (const float*)d_in[0];
  const int*   eidx     = (const int*)d_in[1];
  const int*   batch    = (const int*)d_in[2];
  const float* W_in     = (const float*)d_in[3];
  const float* W_conv   = (const float*)d_in[4];
  const float* W_out    = (const float*)d_in[5];
  const float* b_out    = (const float*)d_in[6];
  float* out            = (float*)d_out;

  const int* src = eidx;            // edge_index[0]
  const int* dst = eidx + N_EDGES;  // edge_index[1]

  float* ws = (float*)d_ws;
  float* H    = ws;                       // 1.6M floats
  float* T    = ws + 1600000;             // 1.6M floats
  float* M    = ws + 3200000;             // 1.6M floats
  float* SUMS = ws + 4800000;             // 4096 floats
  float* CNT  = ws + 4804096;             // 128 floats

  const int node_blocks = (N_NODES + 255) / 256;     // 196
  const int edge_blocks = (N_EDGES * 32) / 256;      // 100000
  const int elem_blocks = (N_NODES * HIDDEN) / 256;  // 6250

  const int WCONV_STRIDE = 2 * HIDDEN * HIDDEN * GRID_SZ;  // 8192

  // input KAN projection: H = KAN_in(x)
  kan_input_v2<<<node_blocks, 256, 0, stream>>>(x, W_in, H);

  // layer 0: T = KAN_0(H)
  kan_node_v2<<<node_blocks, 256, 0, stream>>>(H, nullptr, W_conv, T, nullptr);
  zero_kernel<<<elem_blocks, 256, 0, stream>>>(M, N_NODES * HIDDEN);
  edge_scatter_kernel<<<edge_blocks, 256, 0, stream>>>(T, src, dst, M);

  // layer 1: h1 = leaky(M+H) (written back to H), T = KAN_1(h1)
  kan_node_v2<<<node_blocks, 256, 0, stream>>>(H, M, W_conv + WCONV_STRIDE, T, H);
  zero_kernel<<<elem_blocks, 256, 0, stream>>>(M, N_NODES * HIDDEN);
  edge_scatter_kernel<<<edge_blocks, 256, 0, stream>>>(T, src, dst, M);

  // pool (fused h2 = leaky(M+H)) + readout
  zero_kernel<<<17, 256, 0, stream>>>(SUMS, N_GRAPHS * HIDDEN + N_GRAPHS);
  pool_fused<<<elem_blocks, 256, 0, stream>>>(H, M, batch, SUMS, CNT);
  readout_kernel<<<1, 128, 0, stream>>>(SUMS, CNT, W_out, b_out, out);
}

// Round 4
// 566.466 us; speedup vs baseline: 2.4464x; 2.4464x over previous
//
#include <hip/hip_runtime.h>
#include <math.h>

#define N_NODES   50000
#define N_EDGES   800000
#define IN_FEAT   64
#define HIDDEN    32
#define GRID_SZ   4
#define N_GRAPHS  128
#define NEG_SLOPE 0.01f

// ---------------------------------------------------------------------------
__global__ __launch_bounds__(256) void zero_kernel(float* __restrict__ p, int n) {
  const int i = blockIdx.x * 256 + threadIdx.x;
  if (i < n) p[i] = 0.f;
}

// ---------------------------------------------------------------------------
// Input KAN: 512 threads, 32 nodes/block, thread=(node-pair,o), 2 acc/thread.
// LDS: weights (2,32,64,4)=16384 floats, XOR-swizzled float4 slots;
//      trig[i][node][8] rows padded to 260 floats (bank-start 4i%32).
// ---------------------------------------------------------------------------
__global__ __launch_bounds__(512) void kan_input_v3(
    const float* __restrict__ X, const float* __restrict__ W,
    float* __restrict__ H, int n_nodes) {
  extern __shared__ float smem[];
  float4* __restrict__ w4 = reinterpret_cast<float4*>(smem);   // 4096 float4
  float* __restrict__ tg = smem + 2 * HIDDEN * IN_FEAT * GRID_SZ;  // 64*260
  const int tid = threadIdx.x;
  const int n0 = blockIdx.x * 32;

  // phase 0: stage weights, swizzled so phase-2 reads hit the bank floor
  const float4* __restrict__ Wg = reinterpret_cast<const float4*>(W);
  for (int q = tid; q < 4096; q += 512) {
    const int i = q & 63;
    const int o = (q >> 6) & 31;
    const int slot = (q & ~63) | (i ^ (o & 7));
    w4[slot] = Wg[q];
  }

  // phase 1: trig for 32 nodes x 64 feats (4 pairs/thread)
#pragma unroll
  for (int p = 0; p < 4; ++p) {
    const int idx = p * 512 + tid;
    const int i = idx & 63;
    const int node = idx >> 6;
    const int gn = n0 + node;
    const float v = (gn < n_nodes) ? X[gn * IN_FEAT + i] : 0.f;
    float s1, c1;
    sincosf(v, &s1, &c1);
    const float c2 = c1 * c1 - s1 * s1, s2 = s1 * c1 + c1 * s1;
    const float c3 = c2 * c1 - s2 * s1, s3 = s2 * c1 + c2 * s1;
    const float c4 = c3 * c1 - s3 * s1, s4 = s3 * c1 + c3 * s1;
    const int base = i * 260 + node * 8;
    *reinterpret_cast<float4*>(&tg[base])     = make_float4(c1, c2, c3, c4);
    *reinterpret_cast<float4*>(&tg[base + 4]) = make_float4(s1, s2, s3, s4);
  }
  __syncthreads();

  // phase 2: thread computes H[nA][o], H[nB][o]
  const int o = tid & 31;
  const int row = tid >> 5;       // 0..15
  const int nA = row * 2, nB = nA + 1;
  const int so = o & 7;
  float accA = 0.f, accB = 0.f;
#pragma unroll 4
  for (int i = 0; i < IN_FEAT; ++i) {
    const float4 w0 = w4[o * 64 + (i ^ so)];
    const float4 w1 = w4[2048 + o * 64 + (i ^ so)];
    const float4 cA = *reinterpret_cast<const float4*>(&tg[i * 260 + nA * 8]);
    const float4 sA = *reinterpret_cast<const float4*>(&tg[i * 260 + nA * 8 + 4]);
    const float4 cB = *reinterpret_cast<const float4*>(&tg[i * 260 + nB * 8]);
    const float4 sB = *reinterpret_cast<const float4*>(&tg[i * 260 + nB * 8 + 4]);
    accA += cA.x * w0.x + cA.y * w0.y + cA.z * w0.z + cA.w * w0.w
          + sA.x * w1.x + sA.y * w1.y + sA.z * w1.z + sA.w * w1.w;
    accB += cB.x * w0.x + cB.y * w0.y + cB.z * w0.z + cB.w * w0.w
          + sB.x * w1.x + sB.y * w1.y + sB.z * w1.z + sB.w * w1.w;
  }
  const int gA = n0 + nA, gB = n0 + nB;
  if (gA < n_nodes) H[gA * HIDDEN + o] = accA;
  if (gB < n_nodes) H[gB * HIDDEN + o] = accB;
}

// ---------------------------------------------------------------------------
// Conv KAN: 256 threads, 16 nodes/block (3125*16 = 50000 exact).
// Optionally fuses previous update: v = leaky(Hin+Min), Hout = v.
// ---------------------------------------------------------------------------
__global__ __launch_bounds__(256) void kan_node_v3(
    const float* __restrict__ Hin, const float* __restrict__ Min,
    const float* __restrict__ W, float* __restrict__ T,
    float* __restrict__ Hout) {
  extern __shared__ float smem[];
  float4* __restrict__ w4 = reinterpret_cast<float4*>(smem);   // 2048 float4
  float* __restrict__ tg = smem + 2 * HIDDEN * HIDDEN * GRID_SZ;  // 32*132
  const int tid = threadIdx.x;
  const int n0 = blockIdx.x * 16;

  const float4* __restrict__ Wg = reinterpret_cast<const float4*>(W);
  for (int q = tid; q < 2048; q += 256) {
    const int i = q & 31;
    const int o = (q >> 5) & 31;
    const int slot = (q & ~31) | (i ^ (o & 7));
    w4[slot] = Wg[q];
  }

#pragma unroll
  for (int p = 0; p < 2; ++p) {
    const int idx = p * 256 + tid;
    const int i = idx & 31;
    const int node = idx >> 5;    // 0..15
    const int gn = n0 + node;
    float v = Hin[gn * HIDDEN + i];
    if (Min != nullptr) {
      v += Min[gn * HIDDEN + i];
      v = (v >= 0.f) ? v : NEG_SLOPE * v;
      Hout[gn * HIDDEN + i] = v;
    }
    float s1, c1;
    sincosf(v, &s1, &c1);
    const float c2 = c1 * c1 - s1 * s1, s2 = s1 * c1 + c1 * s1;
    const float c3 = c2 * c1 - s2 * s1, s3 = s2 * c1 + c2 * s1;
    const float c4 = c3 * c1 - s3 * s1, s4 = s3 * c1 + c3 * s1;
    const int base = i * 132 + node * 8;
    *reinterpret_cast<float4*>(&tg[base])     = make_float4(c1, c2, c3, c4);
    *reinterpret_cast<float4*>(&tg[base + 4]) = make_float4(s1, s2, s3, s4);
  }
  __syncthreads();

  const int o = tid & 31;
  const int row = tid >> 5;       // 0..7
  const int nA = row * 2, nB = nA + 1;
  const int so = o & 7;
  float accA = 0.f, accB = 0.f;
#pragma unroll 4
  for (int i = 0; i < HIDDEN; ++i) {
    const float4 w0 = w4[o * 32 + (i ^ so)];
    const float4 w1 = w4[1024 + o * 32 + (i ^ so)];
    const float4 cA = *reinterpret_cast<const float4*>(&tg[i * 132 + nA * 8]);
    const float4 sA = *reinterpret_cast<const float4*>(&tg[i * 132 + nA * 8 + 4]);
    const float4 cB = *reinterpret_cast<const float4*>(&tg[i * 132 + nB * 8]);
    const float4 sB = *reinterpret_cast<const float4*>(&tg[i * 132 + nB * 8 + 4]);
    accA += cA.x * w0.x + cA.y * w0.y + cA.z * w0.z + cA.w * w0.w
          + sA.x * w1.x + sA.y * w1.y + sA.z * w1.z + sA.w * w1.w;
    accB += cB.x * w0.x + cB.y * w0.y + cB.z * w0.z + cB.w * w0.w
          + sB.x * w1.x + sB.y * w1.y + sB.z * w1.z + sB.w * w1.w;
  }
  T[(n0 + nA) * HIDDEN + o] = accA;
  T[(n0 + nB) * HIDDEN + o] = accB;
}

// ---------------------------------------------------------------------------
// m[dst[e]][f] += t[src[e]][f]   (32 threads per edge)
// ---------------------------------------------------------------------------
__global__ __launch_bounds__(256) void edge_scatter_kernel(
    const float* __restrict__ T, const int* __restrict__ src,
    const int* __restrict__ dst, float* __restrict__ M) {
  const int gid = blockIdx.x * 256 + threadIdx.x;
  const int e = gid >> 5;
  const int f = gid & 31;
  if (e < N_EDGES) {
    const int s = src[e];
    const int d = dst[e];
    atomicAdd(&M[d * HIDDEN + f], T[s * HIDDEN + f]);
  }
}

// ---------------------------------------------------------------------------
// pool with fused final update: v = leaky_relu(M+H); per-graph sums/counts
// ---------------------------------------------------------------------------
__global__ __launch_bounds__(256) void pool_fused(
    const float* __restrict__ H, const float* __restrict__ M,
    const int* __restrict__ batch, float* __restrict__ sums,
    float* __restrict__ cnt) {
  const int gid = blockIdx.x * 256 + threadIdx.x;
  const int n = gid >> 5;
  const int f = gid & 31;
  if (n < N_NODES) {
    const int g = batch[n];
    float v = H[n * HIDDEN + f] + M[n * HIDDEN + f];
    v = (v >= 0.f) ? v : NEG_SLOPE * v;
    atomicAdd(&sums[g * HIDDEN + f], v);
    if (f == 0) atomicAdd(&cnt[g], 1.0f);
  }
}

// ---------------------------------------------------------------------------
__global__ __launch_bounds__(128) void readout_kernel(
    const float* __restrict__ sums, const float* __restrict__ cnt,
    const float* __restrict__ Wout, const float* __restrict__ bout,
    float* __restrict__ out) {
  const int g = threadIdx.x;
  if (g < N_GRAPHS) {
    const float c = fmaxf(cnt[g], 1.0f);
    float z = 0.f;
#pragma unroll
    for (int i = 0; i < HIDDEN; ++i) {
      const float y = sums[g * HIDDEN + i] / c;
      z += cosf(y) * Wout[i] + sinf(y) * Wout[HIDDEN + i];
    }
    z += bout[0];
    out[g] = 1.0f / (1.0f + expf(-z));
  }
}

// ---------------------------------------------------------------------------
extern "C" void kernel_launch(void* const* d_in, const int* in_sizes, int n_in,
                              void* d_out, int out_size, void* d_ws, size_t ws_size,
                              hipStream_t stream) {
  const float* x        = (const float*)d_in[0];
  const int*   eidx     = (const int*)d_in[1];
  const int*   batch    = (const int*)d_in[2];
  const float* W_in     = (const float*)d_in[3];
  const float* W_conv   = (const float*)d_in[4];
  const float* W_out    = (const float*)d_in[5];
  const float* b_out    = (const float*)d_in[6];
  float* out            = (float*)d_out;

  const int* src = eidx;            // edge_index[0]
  const int* dst = eidx + N_EDGES;  // edge_index[1]

  float* ws = (float*)d_ws;
  float* H    = ws;                       // 1.6M floats
  float* T    = ws + 1600000;             // 1.6M floats
  float* M    = ws + 3200000;             // 1.6M floats
  float* SUMS = ws + 4800000;             // 4096 floats
  float* CNT  = ws + 4804096;             // 128 floats

  const int in_blocks   = (N_NODES + 31) / 32;       // 1563
  const int conv_blocks = N_NODES / 16;              // 3125
  const int edge_blocks = (N_EDGES * 32) / 256;      // 100000
  const int elem_blocks = (N_NODES * HIDDEN) / 256;  // 6250

  const size_t in_lds   = (size_t)(2*HIDDEN*IN_FEAT*GRID_SZ + IN_FEAT*260) * 4;  // 132096
  const size_t conv_lds = (size_t)(2*HIDDEN*HIDDEN*GRID_SZ + HIDDEN*132) * 4;    // 49664
  const int WCONV_STRIDE = 2 * HIDDEN * HIDDEN * GRID_SZ;  // 8192

  // input KAN projection: H = KAN_in(x)
  kan_input_v3<<<in_blocks, 512, in_lds, stream>>>(x, W_in, H, N_NODES);

  // layer 0: T = KAN_0(H)
  kan_node_v3<<<conv_blocks, 256, conv_lds, stream>>>(H, nullptr, W_conv, T, nullptr);
  zero_kernel<<<elem_blocks, 256, 0, stream>>>(M, N_NODES * HIDDEN);
  edge_scatter_kernel<<<edge_blocks, 256, 0, stream>>>(T, src, dst, M);

  // layer 1: h1 = leaky(M+H) (fused, written to H), T = KAN_1(h1)
  kan_node_v3<<<conv_blocks, 256, conv_lds, stream>>>(H, M, W_conv + WCONV_STRIDE, T, H);
  zero_kernel<<<elem_blocks, 256, 0, stream>>>(M, N_NODES * HIDDEN);
  edge_scatter_kernel<<<edge_blocks, 256, 0, stream>>>(T, src, dst, M);

  // pool (fused h2 = leaky(M+H)) + readout
  zero_kernel<<<17, 256, 0, stream>>>(SUMS, N_GRAPHS * HIDDEN + N_GRAPHS);
  pool_fused<<<elem_blocks, 256, 0, stream>>>(H, M, batch, SUMS, CNT);
  readout_kernel<<<1, 128, 0, stream>>>(SUMS, CNT, W_out, b_out, out);
}

// Round 5
// 492.424 us; speedup vs baseline: 2.8143x; 1.1504x over previous
//
#include <hip/hip_runtime.h>
#include <math.h>

#define N_NODES   50000
#define N_EDGES   800000
#define IN_FEAT   64
#define HIDDEN    32
#define GRID_SZ   4
#define N_GRAPHS  128
#define NEG_SLOPE 0.01f

// ---------------------------------------------------------------------------
__global__ __launch_bounds__(256) void zero_int_kernel(int* __restrict__ p, int n) {
  const int i = blockIdx.x * 256 + threadIdx.x;
  if (i < n) p[i] = 0;
}
__global__ __launch_bounds__(256) void zero_kernel(float* __restrict__ p, int n) {
  const int i = blockIdx.x * 256 + threadIdx.x;
  if (i < n) p[i] = 0.f;
}

// ---------------------------------------------------------------------------
// CSR build: histogram of dst into cursor[]
// ---------------------------------------------------------------------------
__global__ __launch_bounds__(256) void hist_kernel(
    const int* __restrict__ dst, int* __restrict__ cursor) {
  const int e = blockIdx.x * 256 + threadIdx.x;
  if (e < N_EDGES) atomicAdd(&cursor[dst[e]], 1);
}

// single-block exclusive scan over deg (in cursor) -> row_ptr; cursor := row_ptr
__global__ __launch_bounds__(1024) void scan_kernel(
    int* __restrict__ cursor, int* __restrict__ row_ptr) {
  __shared__ int part[1024];
  const int t = threadIdx.x;
  const int PER = (N_NODES + 1023) / 1024;  // 49
  const int lo = t * PER;
  const int hi = (lo + PER < N_NODES) ? lo + PER : N_NODES;
  int sum = 0;
  for (int i = lo; i < hi; ++i) sum += cursor[i];
  part[t] = sum;
  __syncthreads();
  // Hillis-Steele inclusive scan on 1024 partials
  for (int ofs = 1; ofs < 1024; ofs <<= 1) {
    int v = (t >= ofs) ? part[t - ofs] : 0;
    __syncthreads();
    part[t] += v;
    __syncthreads();
  }
  int running = (t == 0) ? 0 : part[t - 1];  // exclusive prefix of this range
  for (int i = lo; i < hi; ++i) {
    const int d = cursor[i];
    row_ptr[i] = running;
    cursor[i] = running;
    running += d;
  }
  if (t == 1023) row_ptr[N_NODES] = part[1023];
}

// fill: adj[pos] = src, pos = cursor[dst]++
__global__ __launch_bounds__(256) void fill_kernel(
    const int* __restrict__ src, const int* __restrict__ dst,
    int* __restrict__ cursor, int* __restrict__ adj) {
  const int e = blockIdx.x * 256 + threadIdx.x;
  if (e < N_EDGES) {
    const int pos = atomicAdd(&cursor[dst[e]], 1);
    adj[pos] = src[e];
  }
}

// ---------------------------------------------------------------------------
// gather + fused update: H[n] = leaky(H[n] + sum_{k in row(n)} T[adj[k]])
// thread = (node, feat); 32-lane groups stream coalesced 128B rows of T.
// ---------------------------------------------------------------------------
__global__ __launch_bounds__(256) void gather_update_kernel(
    const float* __restrict__ T, const int* __restrict__ row_ptr,
    const int* __restrict__ adj, float* __restrict__ H) {
  const int gid = blockIdx.x * 256 + threadIdx.x;
  const int n = gid >> 5;
  const int f = gid & 31;
  if (n >= N_NODES) return;
  const int lo = row_ptr[n], hi = row_ptr[n + 1];
  float acc = 0.f;
  for (int k = lo; k < hi; ++k) {
    const int s = adj[k];
    acc += T[s * HIDDEN + f];
  }
  float v = H[n * HIDDEN + f] + acc;
  v = (v >= 0.f) ? v : NEG_SLOPE * v;
  H[n * HIDDEN + f] = v;
}

// ---------------------------------------------------------------------------
// Input KAN: 512 threads, 32 nodes/block, thread=(node-pair,o), 2 acc/thread.
// ---------------------------------------------------------------------------
__global__ __launch_bounds__(512) void kan_input_v3(
    const float* __restrict__ X, const float* __restrict__ W,
    float* __restrict__ H, int n_nodes) {
  extern __shared__ float smem[];
  float4* __restrict__ w4 = reinterpret_cast<float4*>(smem);   // 4096 float4
  float* __restrict__ tg = smem + 2 * HIDDEN * IN_FEAT * GRID_SZ;  // 64*260
  const int tid = threadIdx.x;
  const int n0 = blockIdx.x * 32;

  const float4* __restrict__ Wg = reinterpret_cast<const float4*>(W);
  for (int q = tid; q < 4096; q += 512) {
    const int i = q & 63;
    const int o = (q >> 6) & 31;
    const int slot = (q & ~63) | (i ^ (o & 7));
    w4[slot] = Wg[q];
  }

#pragma unroll
  for (int p = 0; p < 4; ++p) {
    const int idx = p * 512 + tid;
    const int i = idx & 63;
    const int node = idx >> 6;
    const int gn = n0 + node;
    const float v = (gn < n_nodes) ? X[gn * IN_FEAT + i] : 0.f;
    float s1, c1;
    sincosf(v, &s1, &c1);
    const float c2 = c1 * c1 - s1 * s1, s2 = s1 * c1 + c1 * s1;
    const float c3 = c2 * c1 - s2 * s1, s3 = s2 * c1 + c2 * s1;
    const float c4 = c3 * c1 - s3 * s1, s4 = s3 * c1 + c3 * s1;
    const int base = i * 260 + node * 8;
    *reinterpret_cast<float4*>(&tg[base])     = make_float4(c1, c2, c3, c4);
    *reinterpret_cast<float4*>(&tg[base + 4]) = make_float4(s1, s2, s3, s4);
  }
  __syncthreads();

  const int o = tid & 31;
  const int row = tid >> 5;       // 0..15
  const int nA = row * 2, nB = nA + 1;
  const int so = o & 7;
  float accA = 0.f, accB = 0.f;
#pragma unroll 4
  for (int i = 0; i < IN_FEAT; ++i) {
    const float4 w0 = w4[o * 64 + (i ^ so)];
    const float4 w1 = w4[2048 + o * 64 + (i ^ so)];
    const float4 cA = *reinterpret_cast<const float4*>(&tg[i * 260 + nA * 8]);
    const float4 sA = *reinterpret_cast<const float4*>(&tg[i * 260 + nA * 8 + 4]);
    const float4 cB = *reinterpret_cast<const float4*>(&tg[i * 260 + nB * 8]);
    const float4 sB = *reinterpret_cast<const float4*>(&tg[i * 260 + nB * 8 + 4]);
    accA += cA.x * w0.x + cA.y * w0.y + cA.z * w0.z + cA.w * w0.w
          + sA.x * w1.x + sA.y * w1.y + sA.z * w1.z + sA.w * w1.w;
    accB += cB.x * w0.x + cB.y * w0.y + cB.z * w0.z + cB.w * w0.w
          + sB.x * w1.x + sB.y * w1.y + sB.z * w1.z + sB.w * w1.w;
  }
  const int gA = n0 + nA, gB = n0 + nB;
  if (gA < n_nodes) H[gA * HIDDEN + o] = accA;
  if (gB < n_nodes) H[gB * HIDDEN + o] = accB;
}

// ---------------------------------------------------------------------------
// Conv KAN: 256 threads, 16 nodes/block (3125*16 = 50000 exact).
// ---------------------------------------------------------------------------
__global__ __launch_bounds__(256) void kan_node_v3(
    const float* __restrict__ Hin, const float* __restrict__ W,
    float* __restrict__ T) {
  extern __shared__ float smem[];
  float4* __restrict__ w4 = reinterpret_cast<float4*>(smem);   // 2048 float4
  float* __restrict__ tg = smem + 2 * HIDDEN * HIDDEN * GRID_SZ;  // 32*132
  const int tid = threadIdx.x;
  const int n0 = blockIdx.x * 16;

  const float4* __restrict__ Wg = reinterpret_cast<const float4*>(W);
  for (int q = tid; q < 2048; q += 256) {
    const int i = q & 31;
    const int o = (q >> 5) & 31;
    const int slot = (q & ~31) | (i ^ (o & 7));
    w4[slot] = Wg[q];
  }

#pragma unroll
  for (int p = 0; p < 2; ++p) {
    const int idx = p * 256 + tid;
    const int i = idx & 31;
    const int node = idx >> 5;    // 0..15
    const int gn = n0 + node;
    const float v = Hin[gn * HIDDEN + i];
    float s1, c1;
    sincosf(v, &s1, &c1);
    const float c2 = c1 * c1 - s1 * s1, s2 = s1 * c1 + c1 * s1;
    const float c3 = c2 * c1 - s2 * s1, s3 = s2 * c1 + c2 * s1;
    const float c4 = c3 * c1 - s3 * s1, s4 = s3 * c1 + c3 * s1;
    const int base = i * 132 + node * 8;
    *reinterpret_cast<float4*>(&tg[base])     = make_float4(c1, c2, c3, c4);
    *reinterpret_cast<float4*>(&tg[base + 4]) = make_float4(s1, s2, s3, s4);
  }
  __syncthreads();

  const int o = tid & 31;
  const int row = tid >> 5;       // 0..7
  const int nA = row * 2, nB = nA + 1;
  const int so = o & 7;
  float accA = 0.f, accB = 0.f;
#pragma unroll 4
  for (int i = 0; i < HIDDEN; ++i) {
    const float4 w0 = w4[o * 32 + (i ^ so)];
    const float4 w1 = w4[1024 + o * 32 + (i ^ so)];
    const float4 cA = *reinterpret_cast<const float4*>(&tg[i * 132 + nA * 8]);
    const float4 sA = *reinterpret_cast<const float4*>(&tg[i * 132 + nA * 8 + 4]);
    const float4 cB = *reinterpret_cast<const float4*>(&tg[i * 132 + nB * 8]);
    const float4 sB = *reinterpret_cast<const float4*>(&tg[i * 132 + nB * 8 + 4]);
    accA += cA.x * w0.x + cA.y * w0.y + cA.z * w0.z + cA.w * w0.w
          + sA.x * w1.x + sA.y * w1.y + sA.z * w1.z + sA.w * w1.w;
    accB += cB.x * w0.x + cB.y * w0.y + cB.z * w0.z + cB.w * w0.w
          + sB.x * w1.x + sB.y * w1.y + sB.z * w1.z + sB.w * w1.w;
  }
  T[(n0 + nA) * HIDDEN + o] = accA;
  T[(n0 + nB) * HIDDEN + o] = accB;
}

// ---------------------------------------------------------------------------
// pool via run-length over sorted batch: thread = (range r, feat f)
// ---------------------------------------------------------------------------
#define POOL_RANGES 512
__global__ __launch_bounds__(256) void pool_rl(
    const float* __restrict__ H, const int* __restrict__ batch,
    float* __restrict__ sums, float* __restrict__ cnt) {
  const int tid = threadIdx.x;
  const int f = tid & 31;
  const int r = blockIdx.x * 8 + (tid >> 5);
  const int PER = (N_NODES + POOL_RANGES - 1) / POOL_RANGES;  // 98
  int n = r * PER;
  const int end = (n + PER < N_NODES) ? n + PER : N_NODES;
  if (n >= end) return;
  int g = batch[n];
  float acc = 0.f, c = 0.f;
  for (; n < end; ++n) {
    const int gn = batch[n];
    if (gn != g) {
      atomicAdd(&sums[g * HIDDEN + f], acc);
      if (f == 0) atomicAdd(&cnt[g], c);
      g = gn; acc = 0.f; c = 0.f;
    }
    acc += H[n * HIDDEN + f];
    c += 1.f;
  }
  atomicAdd(&sums[g * HIDDEN + f], acc);
  if (f == 0) atomicAdd(&cnt[g], c);
}

// ---------------------------------------------------------------------------
__global__ __launch_bounds__(128) void readout_kernel(
    const float* __restrict__ sums, const float* __restrict__ cnt,
    const float* __restrict__ Wout, const float* __restrict__ bout,
    float* __restrict__ out) {
  const int g = threadIdx.x;
  if (g < N_GRAPHS) {
    const float c = fmaxf(cnt[g], 1.0f);
    float z = 0.f;
#pragma unroll
    for (int i = 0; i < HIDDEN; ++i) {
      const float y = sums[g * HIDDEN + i] / c;
      z += cosf(y) * Wout[i] + sinf(y) * Wout[HIDDEN + i];
    }
    z += bout[0];
    out[g] = 1.0f / (1.0f + expf(-z));
  }
}

// ---------------------------------------------------------------------------
extern "C" void kernel_launch(void* const* d_in, const int* in_sizes, int n_in,
                              void* d_out, int out_size, void* d_ws, size_t ws_size,
                              hipStream_t stream) {
  const float* x        = (const float*)d_in[0];
  const int*   eidx     = (const int*)d_in[1];
  const int*   batch    = (const int*)d_in[2];
  const float* W_in     = (const float*)d_in[3];
  const float* W_conv   = (const float*)d_in[4];
  const float* W_out    = (const float*)d_in[5];
  const float* b_out    = (const float*)d_in[6];
  float* out            = (float*)d_out;

  const int* src = eidx;            // edge_index[0]
  const int* dst = eidx + N_EDGES;  // edge_index[1]

  float* ws = (float*)d_ws;
  float* H       = ws;                         // 1.6M floats
  float* T       = ws + 1600000;               // 1.6M floats
  int*   row_ptr = (int*)(ws + 3200000);       // 50001 ints
  int*   cursor  = row_ptr + 50008;            // 50000 ints
  int*   adj     = cursor + 50000;             // 800000 ints
  float* SUMS    = (float*)(adj + 800000);     // 4096
  float* CNT     = SUMS + 4096;                // 128

  const int in_blocks   = (N_NODES + 31) / 32;       // 1563
  const int conv_blocks = N_NODES / 16;              // 3125
  const int edge_blocks = (N_EDGES + 255) / 256;     // 3125
  const int gath_blocks = (N_NODES * 32) / 256;      // 6250

  const size_t in_lds   = (size_t)(2*HIDDEN*IN_FEAT*GRID_SZ + IN_FEAT*260) * 4;  // 132096
  const size_t conv_lds = (size_t)(2*HIDDEN*HIDDEN*GRID_SZ + HIDDEN*132) * 4;    // 49664
  const int WCONV_STRIDE = 2 * HIDDEN * HIDDEN * GRID_SZ;  // 8192

  // --- CSR build (overlaps kan_input on the same stream serially; all cheap)
  zero_int_kernel<<<(50000 + 255) / 256, 256, 0, stream>>>(cursor, 50000);
  hist_kernel<<<edge_blocks, 256, 0, stream>>>(dst, cursor);
  scan_kernel<<<1, 1024, 0, stream>>>(cursor, row_ptr);
  fill_kernel<<<edge_blocks, 256, 0, stream>>>(src, dst, cursor, adj);

  // --- input KAN projection: H = KAN_in(x)
  kan_input_v3<<<in_blocks, 512, in_lds, stream>>>(x, W_in, H, N_NODES);

  // --- layer 0: T = KAN_0(H); H = leaky(H + gather(T))
  kan_node_v3<<<conv_blocks, 256, conv_lds, stream>>>(H, W_conv, T);
  gather_update_kernel<<<gath_blocks, 256, 0, stream>>>(T, row_ptr, adj, H);

  // --- layer 1
  kan_node_v3<<<conv_blocks, 256, conv_lds, stream>>>(H, W_conv + WCONV_STRIDE, T);
  gather_update_kernel<<<gath_blocks, 256, 0, stream>>>(T, row_ptr, adj, H);

  // --- pool + readout
  zero_kernel<<<17, 256, 0, stream>>>(SUMS, N_GRAPHS * HIDDEN + N_GRAPHS);
  pool_rl<<<POOL_RANGES / 8, 256, 0, stream>>>(H, batch, SUMS, CNT);
  readout_kernel<<<1, 128, 0, stream>>>(SUMS, CNT, W_out, b_out, out);
}

// Round 6
// 396.580 us; speedup vs baseline: 3.4944x; 1.2417x over previous
//
#include <hip/hip_runtime.h>
#include <math.h>

#define N_NODES   50000
#define N_EDGES   800000
#define IN_FEAT   64
#define HIDDEN    32
#define GRID_SZ   4
#define N_GRAPHS  128
#define NEG_SLOPE 0.01f
#define SCAN_BLOCKS 196   // ceil(50000/256)

// ---------------------------------------------------------------------------
__global__ __launch_bounds__(256) void zero_int_kernel(int* __restrict__ p, int n) {
  const int i = blockIdx.x * 256 + threadIdx.x;
  if (i < n) p[i] = 0;
}
__global__ __launch_bounds__(256) void zero_kernel(float* __restrict__ p, int n) {
  const int i = blockIdx.x * 256 + threadIdx.x;
  if (i < n) p[i] = 0.f;
}

// ---------------------------------------------------------------------------
// CSR build: histogram of dst into deg[]
// ---------------------------------------------------------------------------
__global__ __launch_bounds__(256) void hist_kernel(
    const int* __restrict__ dst, int* __restrict__ deg) {
  const int e = blockIdx.x * 256 + threadIdx.x;
  if (e < N_EDGES) atomicAdd(&deg[dst[e]], 1);
}

// multi-block scan, step A: per-block sums of deg -> bsum[SCAN_BLOCKS]
__global__ __launch_bounds__(256) void scanA_kernel(
    const int* __restrict__ deg, int* __restrict__ bsum) {
  const int i = blockIdx.x * 256 + threadIdx.x;
  int v = (i < N_NODES) ? deg[i] : 0;
#pragma unroll
  for (int o = 32; o > 0; o >>= 1) v += __shfl_down(v, o, 64);
  __shared__ int ws[4];
  if ((threadIdx.x & 63) == 0) ws[threadIdx.x >> 6] = v;
  __syncthreads();
  if (threadIdx.x == 0) bsum[blockIdx.x] = ws[0] + ws[1] + ws[2] + ws[3];
}

// step B: single small block scans the 196 block sums -> exclusive offsets
__global__ __launch_bounds__(256) void scanB_kernel(
    int* __restrict__ bsum, int* __restrict__ row_ptr) {
  __shared__ int sh[256];
  const int t = threadIdx.x;
  int v = (t < SCAN_BLOCKS) ? bsum[t] : 0;
  sh[t] = v;
  __syncthreads();
  for (int o = 1; o < 256; o <<= 1) {
    const int u = (t >= o) ? sh[t - o] : 0;
    __syncthreads();
    sh[t] += u;
    __syncthreads();
  }
  bsum[t] = (t == 0) ? 0 : sh[t - 1];   // exclusive
  if (t == 0) row_ptr[N_NODES] = N_EDGES;
}

// step C: per-block exclusive scan + block offset -> row_ptr, cursor
__global__ __launch_bounds__(256) void scanC_kernel(
    const int* __restrict__ deg, const int* __restrict__ bsum,
    int* __restrict__ row_ptr, int* __restrict__ cursor) {
  __shared__ int sh[256];
  const int t = threadIdx.x;
  const int i = blockIdx.x * 256 + t;
  const int v = (i < N_NODES) ? deg[i] : 0;
  sh[t] = v;
  __syncthreads();
  for (int o = 1; o < 256; o <<= 1) {
    const int u = (t >= o) ? sh[t - o] : 0;
    __syncthreads();
    sh[t] += u;
    __syncthreads();
  }
  if (i < N_NODES) {
    const int excl = bsum[blockIdx.x] + sh[t] - v;
    row_ptr[i] = excl;
    cursor[i] = excl;
  }
}

// fill: adj[pos] = src, pos = cursor[dst]++
__global__ __launch_bounds__(256) void fill_kernel(
    const int* __restrict__ src, const int* __restrict__ dst,
    int* __restrict__ cursor, int* __restrict__ adj) {
  const int e = blockIdx.x * 256 + threadIdx.x;
  if (e < N_EDGES) {
    const int pos = atomicAdd(&cursor[dst[e]], 1);
    adj[pos] = src[e];
  }
}

// ---------------------------------------------------------------------------
// gather + fused update: H[n] = leaky(H[n] + sum_{k in row(n)} T[adj[k]])
// ---------------------------------------------------------------------------
__global__ __launch_bounds__(256) void gather_update_kernel(
    const float* __restrict__ T, const int* __restrict__ row_ptr,
    const int* __restrict__ adj, float* __restrict__ H) {
  const int gid = blockIdx.x * 256 + threadIdx.x;
  const int n = gid >> 5;
  const int f = gid & 31;
  if (n >= N_NODES) return;
  const int lo = row_ptr[n], hi = row_ptr[n + 1];
  float acc = 0.f;
  for (int k = lo; k < hi; ++k) {
    const int s = adj[k];
    acc += T[s * HIDDEN + f];
  }
  float v = H[n * HIDDEN + f] + acc;
  v = (v >= 0.f) ? v : NEG_SLOPE * v;
  H[n * HIDDEN + f] = v;
}

// ---------------------------------------------------------------------------
// Input KAN: 512 threads, 32 nodes/block, thread=(node-pair,o), 2 acc/thread.
// ---------------------------------------------------------------------------
__global__ __launch_bounds__(512) void kan_input_v3(
    const float* __restrict__ X, const float* __restrict__ W,
    float* __restrict__ H, int n_nodes) {
  extern __shared__ float smem[];
  float4* __restrict__ w4 = reinterpret_cast<float4*>(smem);   // 4096 float4
  float* __restrict__ tg = smem + 2 * HIDDEN * IN_FEAT * GRID_SZ;  // 64*260
  const int tid = threadIdx.x;
  const int n0 = blockIdx.x * 32;

  const float4* __restrict__ Wg = reinterpret_cast<const float4*>(W);
  for (int q = tid; q < 4096; q += 512) {
    const int i = q & 63;
    const int o = (q >> 6) & 31;
    const int slot = (q & ~63) | (i ^ (o & 7));
    w4[slot] = Wg[q];
  }

#pragma unroll
  for (int p = 0; p < 4; ++p) {
    const int idx = p * 512 + tid;
    const int i = idx & 63;
    const int node = idx >> 6;
    const int gn = n0 + node;
    const float v = (gn < n_nodes) ? X[gn * IN_FEAT + i] : 0.f;
    float s1, c1;
    sincosf(v, &s1, &c1);
    const float c2 = c1 * c1 - s1 * s1, s2 = s1 * c1 + c1 * s1;
    const float c3 = c2 * c1 - s2 * s1, s3 = s2 * c1 + c2 * s1;
    const float c4 = c3 * c1 - s3 * s1, s4 = s3 * c1 + c3 * s1;
    const int base = i * 260 + node * 8;
    *reinterpret_cast<float4*>(&tg[base])     = make_float4(c1, c2, c3, c4);
    *reinterpret_cast<float4*>(&tg[base + 4]) = make_float4(s1, s2, s3, s4);
  }
  __syncthreads();

  const int o = tid & 31;
  const int row = tid >> 5;       // 0..15
  const int nA = row * 2, nB = nA + 1;
  const int so = o & 7;
  float accA = 0.f, accB = 0.f;
#pragma unroll 4
  for (int i = 0; i < IN_FEAT; ++i) {
    const float4 w0 = w4[o * 64 + (i ^ so)];
    const float4 w1 = w4[2048 + o * 64 + (i ^ so)];
    const float4 cA = *reinterpret_cast<const float4*>(&tg[i * 260 + nA * 8]);
    const float4 sA = *reinterpret_cast<const float4*>(&tg[i * 260 + nA * 8 + 4]);
    const float4 cB = *reinterpret_cast<const float4*>(&tg[i * 260 + nB * 8]);
    const float4 sB = *reinterpret_cast<const float4*>(&tg[i * 260 + nB * 8 + 4]);
    accA += cA.x * w0.x + cA.y * w0.y + cA.z * w0.z + cA.w * w0.w
          + sA.x * w1.x + sA.y * w1.y + sA.z * w1.z + sA.w * w1.w;
    accB += cB.x * w0.x + cB.y * w0.y + cB.z * w0.z + cB.w * w0.w
          + sB.x * w1.x + sB.y * w1.y + sB.z * w1.z + sB.w * w1.w;
  }
  const int gA = n0 + nA, gB = n0 + nB;
  if (gA < n_nodes) H[gA * HIDDEN + o] = accA;
  if (gB < n_nodes) H[gB * HIDDEN + o] = accB;
}

// ---------------------------------------------------------------------------
// Conv KAN: 256 threads, 16 nodes/block (3125*16 = 50000 exact).
// ---------------------------------------------------------------------------
__global__ __launch_bounds__(256) void kan_node_v3(
    const float* __restrict__ Hin, const float* __restrict__ W,
    float* __restrict__ T) {
  extern __shared__ float smem[];
  float4* __restrict__ w4 = reinterpret_cast<float4*>(smem);   // 2048 float4
  float* __restrict__ tg = smem + 2 * HIDDEN * HIDDEN * GRID_SZ;  // 32*132
  const int tid = threadIdx.x;
  const int n0 = blockIdx.x * 16;

  const float4* __restrict__ Wg = reinterpret_cast<const float4*>(W);
  for (int q = tid; q < 2048; q += 256) {
    const int i = q & 31;
    const int o = (q >> 5) & 31;
    const int slot = (q & ~31) | (i ^ (o & 7));
    w4[slot] = Wg[q];
  }

#pragma unroll
  for (int p = 0; p < 2; ++p) {
    const int idx = p * 256 + tid;
    const int i = idx & 31;
    const int node = idx >> 5;    // 0..15
    const int gn = n0 + node;
    const float v = Hin[gn * HIDDEN + i];
    float s1, c1;
    sincosf(v, &s1, &c1);
    const float c2 = c1 * c1 - s1 * s1, s2 = s1 * c1 + c1 * s1;
    const float c3 = c2 * c1 - s2 * s1, s3 = s2 * c1 + c2 * s1;
    const float c4 = c3 * c1 - s3 * s1, s4 = s3 * c1 + c3 * s1;
    const int base = i * 132 + node * 8;
    *reinterpret_cast<float4*>(&tg[base])     = make_float4(c1, c2, c3, c4);
    *reinterpret_cast<float4*>(&tg[base + 4]) = make_float4(s1, s2, s3, s4);
  }
  __syncthreads();

  const int o = tid & 31;
  const int row = tid >> 5;       // 0..7
  const int nA = row * 2, nB = nA + 1;
  const int so = o & 7;
  float accA = 0.f, accB = 0.f;
#pragma unroll 4
  for (int i = 0; i < HIDDEN; ++i) {
    const float4 w0 = w4[o * 32 + (i ^ so)];
    const float4 w1 = w4[1024 + o * 32 + (i ^ so)];
    const float4 cA = *reinterpret_cast<const float4*>(&tg[i * 132 + nA * 8]);
    const float4 sA = *reinterpret_cast<const float4*>(&tg[i * 132 + nA * 8 + 4]);
    const float4 cB = *reinterpret_cast<const float4*>(&tg[i * 132 + nB * 8]);
    const float4 sB = *reinterpret_cast<const float4*>(&tg[i * 132 + nB * 8 + 4]);
    accA += cA.x * w0.x + cA.y * w0.y + cA.z * w0.z + cA.w * w0.w
          + sA.x * w1.x + sA.y * w1.y + sA.z * w1.z + sA.w * w1.w;
    accB += cB.x * w0.x + cB.y * w0.y + cB.z * w0.z + cB.w * w0.w
          + sB.x * w1.x + sB.y * w1.y + sB.z * w1.z + sB.w * w1.w;
  }
  T[(n0 + nA) * HIDDEN + o] = accA;
  T[(n0 + nB) * HIDDEN + o] = accB;
}

// ---------------------------------------------------------------------------
// pool via run-length over sorted batch: thread = (range r, feat f)
// ---------------------------------------------------------------------------
#define POOL_RANGES 512
__global__ __launch_bounds__(256) void pool_rl(
    const float* __restrict__ H, const int* __restrict__ batch,
    float* __restrict__ sums, float* __restrict__ cnt) {
  const int tid = threadIdx.x;
  const int f = tid & 31;
  const int r = blockIdx.x * 8 + (tid >> 5);
  const int PER = (N_NODES + POOL_RANGES - 1) / POOL_RANGES;  // 98
  int n = r * PER;
  const int end = (n + PER < N_NODES) ? n + PER : N_NODES;
  if (n >= end) return;
  int g = batch[n];
  float acc = 0.f, c = 0.f;
  for (; n < end; ++n) {
    const int gn = batch[n];
    if (gn != g) {
      atomicAdd(&sums[g * HIDDEN + f], acc);
      if (f == 0) atomicAdd(&cnt[g], c);
      g = gn; acc = 0.f; c = 0.f;
    }
    acc += H[n * HIDDEN + f];
    c += 1.f;
  }
  atomicAdd(&sums[g * HIDDEN + f], acc);
  if (f == 0) atomicAdd(&cnt[g], c);
}

// ---------------------------------------------------------------------------
__global__ __launch_bounds__(128) void readout_kernel(
    const float* __restrict__ sums, const float* __restrict__ cnt,
    const float* __restrict__ Wout, const float* __restrict__ bout,
    float* __restrict__ out) {
  const int g = threadIdx.x;
  if (g < N_GRAPHS) {
    const float c = fmaxf(cnt[g], 1.0f);
    float z = 0.f;
#pragma unroll
    for (int i = 0; i < HIDDEN; ++i) {
      const float y = sums[g * HIDDEN + i] / c;
      z += cosf(y) * Wout[i] + sinf(y) * Wout[HIDDEN + i];
    }
    z += bout[0];
    out[g] = 1.0f / (1.0f + expf(-z));
  }
}

// ---------------------------------------------------------------------------
extern "C" void kernel_launch(void* const* d_in, const int* in_sizes, int n_in,
                              void* d_out, int out_size, void* d_ws, size_t ws_size,
                              hipStream_t stream) {
  const float* x        = (const float*)d_in[0];
  const int*   eidx     = (const int*)d_in[1];
  const int*   batch    = (const int*)d_in[2];
  const float* W_in     = (const float*)d_in[3];
  const float* W_conv   = (const float*)d_in[4];
  const float* W_out    = (const float*)d_in[5];
  const float* b_out    = (const float*)d_in[6];
  float* out            = (float*)d_out;

  const int* src = eidx;            // edge_index[0]
  const int* dst = eidx + N_EDGES;  // edge_index[1]

  float* ws = (float*)d_ws;
  float* H       = ws;                         // 1.6M floats
  float* T       = ws + 1600000;               // 1.6M floats
  int*   row_ptr = (int*)(ws + 3200000);       // 50001 (pad 50008)
  int*   deg     = row_ptr + 50008;            // 50000 (pad 50048)
  int*   cursor  = deg + 50048;                // 50000 (pad 50048)
  int*   bsum    = cursor + 50048;             // 256
  int*   adj     = bsum + 256;                 // 800000
  float* SUMS    = (float*)(adj + 800000);     // 4096
  float* CNT     = SUMS + 4096;                // 128

  const int in_blocks   = (N_NODES + 31) / 32;       // 1563
  const int conv_blocks = N_NODES / 16;              // 3125
  const int edge_blocks = (N_EDGES + 255) / 256;     // 3125
  const int gath_blocks = (N_NODES * 32) / 256;      // 6250

  const size_t in_lds   = (size_t)(2*HIDDEN*IN_FEAT*GRID_SZ + IN_FEAT*260) * 4;  // 132096
  const size_t conv_lds = (size_t)(2*HIDDEN*HIDDEN*GRID_SZ + HIDDEN*132) * 4;    // 49664
  const int WCONV_STRIDE = 2 * HIDDEN * HIDDEN * GRID_SZ;  // 8192

  // --- CSR build (multi-block scan; every kernel chip-wide)
  zero_int_kernel<<<SCAN_BLOCKS, 256, 0, stream>>>(deg, N_NODES);
  hist_kernel<<<edge_blocks, 256, 0, stream>>>(dst, deg);
  scanA_kernel<<<SCAN_BLOCKS, 256, 0, stream>>>(deg, bsum);
  scanB_kernel<<<1, 256, 0, stream>>>(bsum, row_ptr);
  scanC_kernel<<<SCAN_BLOCKS, 256, 0, stream>>>(deg, bsum, row_ptr, cursor);
  fill_kernel<<<edge_blocks, 256, 0, stream>>>(src, dst, cursor, adj);

  // --- input KAN projection: H = KAN_in(x)
  kan_input_v3<<<in_blocks, 512, in_lds, stream>>>(x, W_in, H, N_NODES);

  // --- layer 0: T = KAN_0(H); H = leaky(H + gather(T))
  kan_node_v3<<<conv_blocks, 256, conv_lds, stream>>>(H, W_conv, T);
  gather_update_kernel<<<gath_blocks, 256, 0, stream>>>(T, row_ptr, adj, H);

  // --- layer 1
  kan_node_v3<<<conv_blocks, 256, conv_lds, stream>>>(H, W_conv + WCONV_STRIDE, T);
  gather_update_kernel<<<gath_blocks, 256, 0, stream>>>(T, row_ptr, adj, H);

  // --- pool + readout
  zero_kernel<<<17, 256, 0, stream>>>(SUMS, N_GRAPHS * HIDDEN + N_GRAPHS);
  pool_rl<<<POOL_RANGES / 8, 256, 0, stream>>>(H, batch, SUMS, CNT);
  readout_kernel<<<1, 128, 0, stream>>>(SUMS, CNT, W_out, b_out, out);
}